// Round 2
// baseline (156.869 us; speedup 1.0000x reference)
//
#include <hip/hip_runtime.h>
#include <stdint.h>

#define N 4096
#define B 2
#define D 128
#define LOG2E 1.4426950408889634f

__device__ __forceinline__ float lrelu(float t) { return t > 0.f ? t : 0.01f * t; }

// K1: u_l[d] = sum_e Wa[e*D+d]*w_l[e]; u_r likewise. 1 block x 256 threads.
// thread t: column-pair d2 = t&63 (cols 2*d2,2*d2+1), e-quarter h = t>>6.
__global__ __launch_bounds__(256) void k1_uvec(
    const float* __restrict__ Wa,
    const float* __restrict__ w_l,
    const float* __restrict__ w_r,
    float* __restrict__ u) {  // u[0..D)=u_l, u[D..2D)=u_r
    __shared__ float2 pl[4][64];
    __shared__ float2 pr[4][64];
    int t = threadIdx.x;
    int d2 = t & 63;
    int h = t >> 6;
    const float2* Wa2 = (const float2*)Wa;
    float2 al = make_float2(0.f, 0.f), ar = make_float2(0.f, 0.f);
    #pragma unroll 8
    for (int k = 0; k < 32; ++k) {
        int e = h * 32 + k;
        float2 w = Wa2[e * 64 + d2];       // Wa[e, 2*d2], Wa[e, 2*d2+1]
        float wl = w_l[e];
        float wr = w_r[e];
        al.x += w.x * wl; al.y += w.y * wl;
        ar.x += w.x * wr; ar.y += w.y * wr;
    }
    pl[h][d2] = al; pr[h][d2] = ar;
    __syncthreads();
    if (t < 64) {
        float2 s = make_float2(0.f, 0.f);
        #pragma unroll
        for (int hh = 0; hh < 4; ++hh) { s.x += pl[hh][t].x; s.y += pl[hh][t].y; }
        ((float2*)u)[t] = s;
    } else if (t < 128) {
        int dd = t - 64;
        float2 s = make_float2(0.f, 0.f);
        #pragma unroll
        for (int hh = 0; hh < 4; ++hh) { s.x += pr[hh][dd].x; s.y += pr[hh][dd].y; }
        ((float2*)(u + D))[dd] = s;
    }
}

// K2: one wave per row. demands (fp32 -> d_out), l,r (pre-scaled by log2e -> ws).
__global__ __launch_bounds__(256) void k2_rows(
    const float* __restrict__ x,     // [B*N, D]
    const float* __restrict__ Wd,    // [D]
    const float* __restrict__ bd,    // [1]
    const float* __restrict__ u,     // [2*D]
    float* __restrict__ out_dem,     // [B*N] (start of d_out)
    float* __restrict__ lv,
    float* __restrict__ rv) {
    int lane = threadIdx.x & 63;
    int row = blockIdx.x * 4 + (threadIdx.x >> 6);
    // lane handles d = 2*lane, 2*lane+1
    float2 xv = ((const float2*)(x + (size_t)row * D))[lane];
    float2 ul2 = ((const float2*)u)[lane];
    float2 ur2 = ((const float2*)(u + D))[lane];
    float2 wv = ((const float2*)Wd)[lane];
    float pl = xv.x * ul2.x + xv.y * ul2.y;
    float pr = xv.x * ur2.x + xv.y * ur2.y;
    float pd = xv.x * wv.x + xv.y * wv.y;
    #pragma unroll
    for (int m = 32; m >= 1; m >>= 1) {
        pl += __shfl_xor(pl, m, 64);
        pr += __shfl_xor(pr, m, 64);
        pd += __shfl_xor(pd, m, 64);
    }
    if (lane == 0) {
        float dem = 1.f / (1.f + __expf(-(pd + bd[0])));
        out_dem[row] = dem;
        lv[row] = pl * LOG2E;   // exp2 domain (lrelu commutes with positive scale)
        rv[row] = pr * LOG2E;
    }
}

// K3: 4 rows per block (same b). Stage r in LDS; rmax reduce; denom pass; write pass.
__global__ __launch_bounds__(256) void k3_main(
    const float* __restrict__ lv, const float* __restrict__ rv,
    const float* __restrict__ dem_f,      // demands (fp32, start of d_out)
    float* __restrict__ out_g) {          // [B,N,N] fp32
    __shared__ float sr[N];
    __shared__ float redmax[4];
    __shared__ float redsum[4][4];
    int tid = threadIdx.x;
    int b = blockIdx.x >> 10;             // /1024 blocks-per-b
    int i0 = (blockIdx.x & 1023) << 2;    // *4 rows
    const float* rb = rv + b * N;
    float lmax = -3.402823466e38f;
    #pragma unroll
    for (int k = 0; k < N / 256; ++k) {
        float v = rb[tid + k * 256];
        sr[tid + k * 256] = v;            // stride-256: 2 lanes/bank -> free
        lmax = fmaxf(lmax, v);
    }
    #pragma unroll
    for (int m = 32; m >= 1; m >>= 1) lmax = fmaxf(lmax, __shfl_xor(lmax, m, 64));
    if ((tid & 63) == 0) redmax[tid >> 6] = lmax;
    __syncthreads();
    float rmax = fmaxf(fmaxf(redmax[0], redmax[1]), fmaxf(redmax[2], redmax[3]));

    int rowbase = b * N + i0;
    float lr_[4], mr[4], s[4];
    #pragma unroll
    for (int q = 0; q < 4; ++q) {
        lr_[q] = lv[rowbase + q];
        mr[q] = lrelu(lr_[q] + rmax);     // true row max (lrelu monotone)
        s[q] = 0.f;
    }
    #pragma unroll 2
    for (int k = 0; k < N / 256; ++k) {
        float r = sr[tid + k * 256];
        #pragma unroll
        for (int q = 0; q < 4; ++q) s[q] += exp2f(lrelu(lr_[q] + r) - mr[q]);
    }
    #pragma unroll
    for (int m = 32; m >= 1; m >>= 1) {
        #pragma unroll
        for (int q = 0; q < 4; ++q) s[q] += __shfl_xor(s[q], m, 64);
    }
    if ((tid & 63) == 0) {
        #pragma unroll
        for (int q = 0; q < 4; ++q) redsum[tid >> 6][q] = s[q];
    }
    __syncthreads();
    float sc[4];
    #pragma unroll
    for (int q = 0; q < 4; ++q) {
        float den = redsum[0][q] + redsum[1][q] + redsum[2][q] + redsum[3][q];
        sc[q] = dem_f[rowbase + q] / den;
    }
    // Write pass: each thread owns one float4 (j = idx*4..idx*4+3) per row:
    // lane i stores at base+16*i -> perfectly coalesced 16B/lane.
    // r re-read from global as float4 (L1-hot; LDS float4 would 8-way conflict).
    const float4* rb4 = (const float4*)rb;
    size_t gbase = (size_t)b * N * N + (size_t)i0 * N;
    #pragma unroll
    for (int it = 0; it < 4; ++it) {
        int idx = it * 256 + tid;          // 0..1023, j0 = idx*4
        float4 r4 = rb4[idx];
        #pragma unroll
        for (int q = 0; q < 4; ++q) {
            float4 o;
            o.x = exp2f(lrelu(lr_[q] + r4.x) - mr[q]) * sc[q];
            o.y = exp2f(lrelu(lr_[q] + r4.y) - mr[q]) * sc[q];
            o.z = exp2f(lrelu(lr_[q] + r4.z) - mr[q]) * sc[q];
            o.w = exp2f(lrelu(lr_[q] + r4.w) - mr[q]) * sc[q];
            *(float4*)(out_g + gbase + (size_t)q * N + (size_t)idx * 4) = o;
        }
    }
}

extern "C" void kernel_launch(void* const* d_in, const int* in_sizes, int n_in,
                              void* d_out, int out_size, void* d_ws, size_t ws_size,
                              hipStream_t stream) {
    // inputs: 0 embed_feat(f32 B*N*D), 1 predict_G(int,ignored), 2 W_demand(f32 D),
    //         3 b_demand(f32 1), 4 Wa(f32 D*D), 5 w_l(f32 D), 6 w_r(f32 D)
    const float* x  = (const float*)d_in[0];
    const float* Wd = (const float*)d_in[2];
    const float* bd = (const float*)d_in[3];
    const float* Wa = (const float*)d_in[4];
    const float* wl = (const float*)d_in[5];
    const float* wr = (const float*)d_in[6];

    float* ws = (float*)d_ws;
    float* u  = ws;                 // 256 floats
    float* lv = ws + 256;           // 8192
    float* rv = ws + 256 + 8192;    // 8192   (total ~66 KB)

    float* out     = (float*)d_out;
    float* out_dem = out;           // [B*N]
    float* out_g   = out + B * N;   // [B,N,N]

    hipLaunchKernelGGL(k1_uvec, dim3(1), dim3(256), 0, stream, Wa, wl, wr, u);
    hipLaunchKernelGGL(k2_rows, dim3(B * N / 4), dim3(256), 0, stream,
                       x, Wd, bd, u, out_dem, lv, rv);
    hipLaunchKernelGGL(k3_main, dim3(B * N / 4), dim3(256), 0, stream,
                       lv, rv, out_dem, out_g);
}